// Round 14
// baseline (84.396 us; speedup 1.0000x reference)
//
#include <hip/hip_runtime.h>

typedef _Float16 h16x8 __attribute__((ext_vector_type(8)));
typedef float f32x4 __attribute__((ext_vector_type(4)));

#define MFMA16F(a, b, c) __builtin_amdgcn_mfma_f32_16x16x32_f16((a), (b), (c), 0, 0, 0)

#define GLOAD16(gp, lp)                                                        \
  __builtin_amdgcn_global_load_lds(                                            \
      (const __attribute__((address_space(1))) unsigned int*)(gp),             \
      (__attribute__((address_space(3))) unsigned int*)(lp), 16, 0, 0)

#define FENCE() __builtin_amdgcn_sched_barrier(0)

// Geometry: x (8, 256, 16384) fp32; mem (200, 256) fp32; out (8, 256, 16384) fp32.
// Slots padded 200 -> 256 with zero rows.
// Score: fp16 2-pass split (R12-proven). PV: R13 orientation (P = A-operand,
// pure-register from score acc; MB = B-frag-tiled mem table, linear LDS reads;
// token-contiguous f32x4 stores).

// ---------------- prep: mem -> fp16 M16 (row-major) + MB (B-frag-tiled) ----------------
__global__ __launch_bounds__(256) void prep_mem(const float* __restrict__ mem,
                                                unsigned short* __restrict__ M16,
                                                unsigned short* __restrict__ MB) {
  const int s = blockIdx.x;   // slot (padded 0..255)
  const int c = threadIdx.x;  // channel
  const float v = (s < 200) ? mem[s * 256 + c] : 0.0f;
  const _Float16 hv = (_Float16)v;
  const unsigned short hb = __builtin_bit_cast(unsigned short, hv);
  M16[s * 256 + c] = hb;
  if (s < 224) {
    // invert s(kk,h,j): s = 32kk + 16*(j>>2) + 4h + (j&3)
    const int kk = s >> 5;
    const int th = (s >> 4) & 1;   // j>>2
    const int hh = (s >> 2) & 3;
    const int rr = s & 3;          // j&3
    const int j = th * 4 + rr;
    MB[kk * 8192 + (c >> 4) * 512 + hh * 128 + (c & 15) * 8 + j] = hb;
  }
}

// ---------------- fused kernel ----------------
// Block = 12 waves x 32 tokens = 384 tokens, 768 threads, grid 342 (tail:
// last block has exactly 4 valid waves -> wave-uniform predication).
// __launch_bounds__(768,3): 3 waves/SIMD, 170 regs/wave -> dual-token-group
// fits (acc[13][2]=104 AGPR + ~62 VGPR). Each score A-frag read feeds 4 MFMAs
// (hi/lo x 2 token groups); each PV B-frag read feeds 2 MFMAs -> LDS traffic
// per token HALVES vs R13.
__global__ __launch_bounds__(768, 3) void fused_mem_attn(
    const float* __restrict__ x, const unsigned short* __restrict__ M16,
    const unsigned short* __restrict__ MB, float* __restrict__ out) {
  __shared__ alignas(128) char lds[131072];

  const int tid = threadIdx.x;   // 0..767
  const int wave = tid >> 6;     // 0..11
  const int lane = tid & 63;
  const int t16 = lane & 15;
  const int h = lane >> 4;

  // Staging ownership: 16KB slice = 1024 16B-blocks over 768 threads.
  // it=0: P=tid; it=1: P=768+tid (only tid<256). Swizzle pair proven R7-R13.
  const int P0 = tid;
  const int L0 = P0 ^ ((P0 >> 3) & 7);
  const int srcOff0 = (L0 >> 2) * 512 + (L0 & 3) * 16;
  const int P1 = 768 + tid;
  const int L1 = P1 ^ ((P1 >> 3) & 7);
  const int srcOff1 = (L1 >> 2) * 512 + (L1 & 3) * 16;
  const bool own1 = (tid < 256);

  // Reader-side swizzled 16B-block offset within a 1KB (16-row) tile.
  const int q16 = ((((t16 << 2) + h) ^ (t16 >> 1)) << 4);

  // Wave's 32 tokens: tw + g*16 + t16 (g=0,1). Tail: whole-wave validity
  // (131072 = 341*384 + 4*32, so waves are never partially valid).
  const long tw_raw = (long)blockIdx.x * 384 + wave * 32;
  const bool wvalid = (tw_raw + 31) < 131072;
  const long tw = wvalid ? tw_raw : 0;

  // Per-lane batch-boundary-safe bases (384 does not divide 16384):
  const long T0 = tw + t16;
  const long T1 = tw + 16 + t16;
  const float* xb0 = x + ((T0 >> 14) << 22) + (T0 & 16383);
  const float* xb1 = x + ((T1 >> 14) << 22) + (T1 & 16383);
  // Store bases: tokens S_g..S_g+3 (always within one batch: S_g % 4 == 0);
  // channel = ct*16 + t16.
  const long S0 = tw + 4 * h;
  const long S1 = tw + 16 + 4 * h;
  float* ob0 = out + ((S0 >> 14) << 22) + (S0 & 16383) + ((long)t16 << 14);
  float* ob1 = out + ((S1 >> 14) << 22) + (S1 & 16383) + ((long)t16 << 14);

  const char* M16B = (const char*)M16;
  const char* MBB = (const char*)MB;

#define XLOAD(ks)                                                              \
  _Pragma("unroll") for (int j = 0; j < 8; ++j) {                              \
    const long o_ = (long)((ks) * 32 + h * 8 + j) << 14;                       \
    xr[(ks) & 1][0][j] = xb0[o_];                                              \
    xr[(ks) & 1][1][j] = xb1[o_];                                              \
  }

  float xr[2][2][8];
  f32x4 acc[13][2] = {};  // 13 tiles x 16 = 208 slots (200 real, 8 masked)

#define COMPUTE(ks)                                                            \
  {                                                                            \
    if ((ks) < 7) XLOAD((ks) + 1);                                             \
    h16x8 xh0, xl0, xh1, xl1;                                                  \
    _Pragma("unroll") for (int j = 0; j < 8; ++j) {                            \
      const float f0 = xr[(ks) & 1][0][j];                                     \
      const float f1 = xr[(ks) & 1][1][j];                                     \
      const _Float16 h0_ = (_Float16)f0;                                       \
      const _Float16 h1_ = (_Float16)f1;                                       \
      xh0[j] = h0_;                                                            \
      xl0[j] = (_Float16)(f0 - (float)h0_);                                    \
      xh1[j] = h1_;                                                            \
      xl1[j] = (_Float16)(f1 - (float)h1_);                                    \
    }                                                                          \
    const char* sb = lds + (ks) * 16384;                                       \
    _Pragma("unroll") for (int tt = 0; tt < 13; ++tt) {                        \
      const h16x8 ah = *(const h16x8*)(sb + tt * 1024 + q16);                  \
      acc[tt][0] = MFMA16F(ah, xh0, acc[tt][0]);                               \
      acc[tt][1] = MFMA16F(ah, xh1, acc[tt][1]);                               \
      acc[tt][0] = MFMA16F(ah, xl0, acc[tt][0]);                               \
      acc[tt][1] = MFMA16F(ah, xl1, acc[tt][1]);                               \
    }                                                                          \
    FENCE();                                                                   \
  }

  // ---- prologue: x prefetch + stage ALL 8 M16 slices; barrier #1 ----
  XLOAD(0);
#pragma unroll
  for (int ks = 0; ks < 8; ++ks) {
    GLOAD16(M16B + srcOff0 + ks * 64, lds + ks * 16384 + P0 * 16);
    if (own1) GLOAD16(M16B + srcOff1 + ks * 64, lds + ks * 16384 + P1 * 16);
  }
  __syncthreads();

  // ---- score phase: BARRIER-FREE (M16 fully resident, bounded x prefetch) ----
  COMPUTE(0) COMPUTE(1) COMPUTE(2) COMPUTE(3)
  COMPUTE(4) COMPUTE(5) COMPUTE(6) COMPUTE(7)

  __syncthreads();  // barrier #2: all waves done reading M16 LDS

  // ---- stage ALL of MB (7 x 16KB, linear both sides) over dead score
  //      slices; latency hides under softmax + repack ----
#pragma unroll
  for (int k = 0; k < 7; ++k) {
    GLOAD16(MBB + k * 16384 + P0 * 16, lds + k * 16384 + P0 * 16);
    if (own1) GLOAD16(MBB + k * 16384 + P1 * 16, lds + k * 16384 + P1 * 16);
  }
  FENCE();

  // ---- softmax per token group (token column = lane&15; slot row = 4h+r) ----
  float inv[2];
#pragma unroll
  for (int g = 0; g < 2; ++g) {
    float m = -3.0e38f;
#pragma unroll
    for (int tt = 0; tt < 12; ++tt)
#pragma unroll
      for (int r = 0; r < 4; ++r) m = fmaxf(m, acc[tt][g][r]);
#pragma unroll
    for (int r = 0; r < 4; ++r)
      if (192 + h * 4 + r < 200) m = fmaxf(m, acc[12][g][r]);
    m = fmaxf(m, __shfl_xor(m, 16, 64));
    m = fmaxf(m, __shfl_xor(m, 32, 64));
    float s = 0.f;
#pragma unroll
    for (int tt = 0; tt < 12; ++tt)
#pragma unroll
      for (int r = 0; r < 4; ++r) {
        const float p = __expf(acc[tt][g][r] - m);
        acc[tt][g][r] = p;
        s += p;
      }
#pragma unroll
    for (int r = 0; r < 4; ++r) {
      const bool ok = (192 + h * 4 + r) < 200;
      const float p = ok ? __expf(acc[12][g][r] - m) : 0.f;
      acc[12][g][r] = p;
      s += p;
    }
    s += __shfl_xor(s, 16, 64);
    s += __shfl_xor(s, 32, 64);
    inv[g] = 1.f / s;
  }

  // ---- repack P into PV A-fragments, inv folded (pure register):
  //      pa[kk][g][j] = inv_g * acc[2kk + (j>>2)][g][j&3]; kk=6,j>=4 hits
  //      slots 208..223 -> exactly 0 via... (those acc entries don't exist:
  //      use 0 explicitly). ----
  h16x8 pa[7][2];
#pragma unroll
  for (int kk = 0; kk < 6; ++kk)
#pragma unroll
    for (int g = 0; g < 2; ++g)
#pragma unroll
      for (int j = 0; j < 8; ++j)
        pa[kk][g][j] = (_Float16)(inv[g] * acc[2 * kk + (j >> 2)][g][j & 3]);
#pragma unroll
  for (int g = 0; g < 2; ++g)
#pragma unroll
    for (int j = 0; j < 8; ++j)
      pa[6][g][j] = (j < 4) ? (_Float16)(inv[g] * acc[12][g][j & 3])
                            : (_Float16)0.f;  // slots 208..223: P = 0

  __syncthreads();  // barrier #3: MB resident

  // ---- PV: D[tok][chan] = P*M. One B-frag read feeds BOTH token groups;
  //      f32x4 = 4 consecutive tokens -> 16B dwordx4 stores ----
#pragma unroll
  for (int ct = 0; ct < 16; ++ct) {
    f32x4 a0 = {0.f, 0.f, 0.f, 0.f};
    f32x4 a1 = {0.f, 0.f, 0.f, 0.f};
#pragma unroll
    for (int kk = 0; kk < 7; ++kk) {
      const h16x8 bt = *(const h16x8*)(lds + kk * 16384 + ct * 1024 + lane * 16);
      a0 = MFMA16F(pa[kk][0], bt, a0);
      a1 = MFMA16F(pa[kk][1], bt, a1);
    }
    if (wvalid) {
      *(f32x4*)(ob0 + ((long)ct << 18)) = a0;
      *(f32x4*)(ob1 + ((long)ct << 18)) = a1;
    }
    FENCE();
  }
#undef XLOAD
#undef COMPUTE
}

extern "C" void kernel_launch(void* const* d_in, const int* in_sizes, int n_in,
                              void* d_out, int out_size, void* d_ws, size_t ws_size,
                              hipStream_t stream) {
  const float* x = (const float*)d_in[0];
  const float* mem = (const float*)d_in[1];
  float* out = (float*)d_out;

  unsigned short* M16 = (unsigned short*)d_ws;   // [256][256] fp16 row-major
  unsigned short* MB = M16 + 256 * 256;          // [7][16][4][16][8] fp16 B-frag tiling

  prep_mem<<<dim3(256), dim3(256), 0, stream>>>(mem, M16, MB);
  // 131072 tokens = 341 full 384-token blocks + one 128-token tail block
  fused_mem_attn<<<dim3(342), dim3(768), 0, stream>>>(x, M16, MB, out);
}